// Round 9
// baseline (58.262 us; speedup 1.0000x reference)
//
#include <hip/hip_runtime.h>
#include <hip/hip_bf16.h>

typedef __attribute__((ext_vector_type(8))) short s16x8;
typedef __attribute__((ext_vector_type(4))) float f32x4;
typedef __attribute__((ext_vector_type(4))) float fl4;

__device__ __forceinline__ unsigned short f2bf(float f) {
  union { __hip_bfloat16 b; unsigned short u; } cv;
  cv.b = __float2bfloat16(f);
  return cv.u;
}

// HSTU fused, B=8 H=4 D=V=64 SEQ=1024.
// R9: R8 skeleton (2048 x 1-wave blocks, no barriers) with the chain fixed:
//  - launch_bounds(64,2): 256 VGPR cap -> loads stay in flight (R8 was 64!)
//  - cross-iter K prefetch: tile t+1's fp32 loads issue before compute(t)
//  - V via per-wave 8KB LDS image: coalesced row loads + R6-verified packed
//    b32 permuted writes + R1-verified b128 frag reads (no barrier: same-wave
//    LDS ordering + lgkmcnt(0))
//  - 1/2048 folded into P (not V)
// V image: short[((kp*4+gg)*64+col)*8 + tu*4 + j] = V[32kp+16tu+4gg+j][col].
__global__ __launch_bounds__(64, 2)
void hstu_fused(const float* __restrict__ tq, const float* __restrict__ tk,
                const float* __restrict__ tv, const int* __restrict__ ncand,
                float* __restrict__ out)
{
  __shared__ unsigned short Vimg[4096];     // one wave per block: private image
  const int bid = (int)blockIdx.x;
  const int bh  = bid & 31;                 // same bh -> same XCD (stride 32)
  const int jp  = bid >> 5;                 // 0..63
  const int rg  = (jp == 0) ? 0 : 64 - jp;  // heavy-first (rg0 = contextual rows)
  const int b = bh >> 2, h = bh & 3;
  const int l = (int)threadIdx.x;
  const int rl = l & 15, g = l >> 4;
  const int T = 1024 - ncand[b];
  const int qr = rg << 4;                   // wave's q-rows [qr, qr+16)
  const int rq = qr + rl;

  // ---- Q frags in-reg (alpha=1/8 folded): lane(rl,g) d in {8g..8g+7} u {32+8g..}
  s16x8 qf0, qf1;
  {
    const float* qs = tq + ((size_t)(b*1024 + rq))*256 + h*64;
    fl4 a  = *(const fl4*)(qs + g*8);
    fl4 b2 = *(const fl4*)(qs + g*8 + 4);
    fl4 c  = *(const fl4*)(qs + 32 + g*8);
    fl4 d2 = *(const fl4*)(qs + 36 + g*8);
#pragma unroll
    for (int j = 0; j < 4; ++j) {
      qf0[j]   = (short)f2bf(a[j]  * 0.125f);
      qf0[j+4] = (short)f2bf(b2[j] * 0.125f);
      qf1[j]   = (short)f2bf(c[j]  * 0.125f);
      qf1[j+4] = (short)f2bf(d2[j] * 0.125f);
    }
  }

  const float* kroot = tk + ((size_t)b*1024)*256 + h*64;
  const float* vroot = tv + ((size_t)b*1024)*256 + h*64;

  // ---- K prefetch regs (fp32) and current bf16 frags
  fl4 kpre[4][4];
  s16x8 kfa[4], kfb[4];

  auto kload = [&](int t) {
#pragma unroll
    for (int t4 = 0; t4 < 4; ++t4) {
      const float* kr = kroot + (size_t)(t*64 + t4*16 + rl)*256;
      kpre[t4][0] = *(const fl4*)(kr + g*8);
      kpre[t4][1] = *(const fl4*)(kr + g*8 + 4);
      kpre[t4][2] = *(const fl4*)(kr + 32 + g*8);
      kpre[t4][3] = *(const fl4*)(kr + 36 + g*8);
    }
  };
  auto kcvt = [&]() {
#pragma unroll
    for (int t4 = 0; t4 < 4; ++t4) {
#pragma unroll
      for (int j = 0; j < 4; ++j) {
        kfa[t4][j]   = (short)f2bf(kpre[t4][0][j]);
        kfa[t4][j+4] = (short)f2bf(kpre[t4][1][j]);
        kfb[t4][j]   = (short)f2bf(kpre[t4][2][j]);
        kfb[t4][j+4] = (short)f2bf(kpre[t4][3][j]);
      }
    }
  };

  f32x4 zero = {0.f, 0.f, 0.f, 0.f};
  f32x4 oacc[4];
#pragma unroll
  for (int i = 0; i < 4; ++i) oacc[i] = zero;

  const int nkv = (rg == 0) ? 16 : (rg >> 2) + 1;   // causal tile bound

  kload(0);
  kcvt();

  unsigned int* vp32 = (unsigned int*)Vimg;
  const int ch  = l & 15;     // V staging: col chunk (4 floats)
  const int pr4 = l >> 4;     // V staging: row-pair sub-index

  for (int t = 0; t < nkv; ++t) {
    // ---- issue V(t) loads early (consumed after QK -> latency hidden)
    fl4 vv0[8], vv1[8];
#pragma unroll
    for (int c = 0; c < 8; ++c) {
      const int p = c*4 + pr4;                       // row-pair 0..31
      const float* vs = vroot + (size_t)(t*64 + 2*p)*256 + ch*4;
      vv0[c] = *(const fl4*)vs;                      // row 2p
      vv1[c] = *(const fl4*)(vs + 256);              // row 2p+1
    }
    // ---- issue K(t+1) loads (stay in flight through V-write+silu+PV)
    if (t + 1 < nkv) kload(t + 1);

    // ---- QK^T swapped from current bf16 K frags
    f32x4 sacc[4];
#pragma unroll
    for (int i = 0; i < 4; ++i) sacc[i] = zero;
#pragma unroll
    for (int t4 = 0; t4 < 4; ++t4) {
      sacc[t4] = __builtin_amdgcn_mfma_f32_16x16x32_bf16(kfa[t4], qf0, sacc[t4], 0, 0, 0);
      sacc[t4] = __builtin_amdgcn_mfma_f32_16x16x32_bf16(kfb[t4], qf1, sacc[t4], 0, 0, 0);
    }

    // ---- V cvt + packed permuted ds_writes (R6-verified mapping)
#pragma unroll
    for (int c = 0; c < 8; ++c) {
      const int p = c*4 + pr4;
      const int y = 2*p;
      const int kp = y >> 5, tu = (y >> 4) & 1, gg = (y >> 2) & 3, j0 = y & 3;
      const int dbase = ((kp*4 + gg)*64 + ch*4)*4 + tu*2 + (j0 >> 1);
#pragma unroll
      for (int ji = 0; ji < 4; ++ji) {
        const unsigned int lo = f2bf(vv0[c][ji]);
        const unsigned int hi = f2bf(vv1[c][ji]);
        vp32[dbase + ji*4] = lo | (hi << 16);
      }
    }

    // ---- silu + mask + pack P (1/2048 folded here)
    s16x8 pa0, pa1;
#pragma unroll
    for (int t4 = 0; t4 < 4; ++t4) {
#pragma unroll
      for (int r = 0; r < 4; ++r) {
        const int y = t*64 + t4*16 + 4*g + r;
        const float s = sacc[t4][r];
        const float sig = __builtin_amdgcn_rcpf(1.f + __expf(-s));
        const bool valid = (rq < 8) ? (y < T)
                         : ((y <= rq) && ((rq < T) || (y < T) || (y == rq)));
        const float a = valid ? s * sig * 4.8828125e-4f : 0.f;
        const short bv = (short)f2bf(a);
        if (t4 < 2) pa0[(t4 & 1)*4 + r] = bv;
        else        pa1[(t4 & 1)*4 + r] = bv;
      }
    }

    // ---- same-wave LDS publish: writes done before frag reads
    asm volatile("s_waitcnt lgkmcnt(0)" ::: "memory");
    __builtin_amdgcn_sched_barrier(0);

    // ---- PV from permuted image (R1-verified b128 reads)
#pragma unroll
    for (int vt = 0; vt < 4; ++vt) {
      const s16x8 vf0 = *(const s16x8*)&Vimg[((0*4 + g)*64 + vt*16 + rl)*8];
      oacc[vt] = __builtin_amdgcn_mfma_f32_16x16x32_bf16(pa0, vf0, oacc[vt], 0, 0, 0);
      const s16x8 vf1 = *(const s16x8*)&Vimg[((1*4 + g)*64 + vt*16 + rl)*8];
      oacc[vt] = __builtin_amdgcn_mfma_f32_16x16x32_bf16(pa1, vf1, oacc[vt], 0, 0, 0);
    }

    // ---- convert prefetched K(t+1) into frags for next iter
    if (t + 1 < nkv) kcvt();
  }

  // ---- epilogue (verified): O[qr + 4g+r][vt*16+rl]
  float* dst = out + ((size_t)(b*1024 + qr))*256 + h*64;
#pragma unroll
  for (int vt = 0; vt < 4; ++vt)
#pragma unroll
    for (int r = 0; r < 4; ++r)
      dst[(size_t)(4*g + r)*256 + vt*16 + rl] = oacc[vt][r];
}

extern "C" void kernel_launch(void* const* d_in, const int* in_sizes, int n_in,
                              void* d_out, int out_size, void* d_ws, size_t ws_size,
                              hipStream_t stream) {
  (void)in_sizes; (void)n_in; (void)out_size; (void)d_ws; (void)ws_size;
  const float* tq = (const float*)d_in[0];
  const float* tk = (const float*)d_in[1];
  const float* tv = (const float*)d_in[2];
  const int*   nc = (const int*)d_in[4];
  float* out = (float*)d_out;
  hipLaunchKernelGGL(hstu_fused, dim3(2048), dim3(64), 0, stream, tq, tk, tv, nc, out);
}